// Round 9
// baseline (2126.536 us; speedup 1.0000x reference)
//
#include <hip/hip_runtime.h>
#include <hip/hip_fp16.h>

// ---------------------------------------------------------------------------
// Heads: per-head QKV projections + causal attention, B=4 T=1024 C=1024 H=8.
// Round 9: 2-blocks/CU GEMM core. 256x256 tile, K-step 32, double-buffered
// [db2][A|B] x 16KB = 64 KB LDS (was 128 KB / 1 block/CU). Per-64K instruction
// densities identical to round 5/8; staging issued after lgkmcnt(0) (race-free
// WAR), counted vmcnt(4) per K-step. Bet: co-resident block hides phase stalls
// (m114 overlap) and de-quantizes the 37us dispatch rounds.
// Schedule/modes = round 8: cast_setup -> MT(128) -> {Q'+VT}(1024) ->
// QK(320 causal) -> softmax16 -> PV(256 paired, uniform work).
// ---------------------------------------------------------------------------

typedef unsigned short u16;
typedef _Float16 f16x8 __attribute__((ext_vector_type(8)));
typedef float f32x4 __attribute__((ext_vector_type(4)));

__device__ __forceinline__ u16 f2h(float f) {
    union { __half h; u16 u; } cv;
    cv.h = __float2half(f);
    return cv.u;
}
__device__ __forceinline__ float h2f(u16 u) {
    union { __half h; u16 u; } cv;
    cv.u = u;
    return __half2float(cv.h);
}

// global -> LDS direct copy, 16B/lane (wave-uniform LDS base + lane*16).
__device__ __forceinline__ void gload_lds16(const u16* g, const u16* lds_base, unsigned off_bytes) {
    unsigned a32 = (unsigned)(uintptr_t)((const char*)lds_base + off_bytes);
    a32 = __builtin_amdgcn_readfirstlane(a32);
    __builtin_amdgcn_global_load_lds(
        (const __attribute__((address_space(1))) void*)(uintptr_t)g,
        (__attribute__((address_space(3))) void*)a32,
        16, 0, 0);
}

#define M_MT 0
#define M_PROJ 1
#define M_QK 2
#define M_PV 3

// ---------------------------------------------------------------------------
// mega<MODE>: 256x256 tile, K-step 32, 8 waves (2Mx4N), per-wave 128x64 out.
// D = scale * A x Bt^T (operands [rows][K] fp16).
//   MT:   128 blocks: MT_h[c'][c] = sum_d WkT[c'][d] WqT[c][d], fp16 out
//   PROJ: 1024 = Q'(512: X x MT_h) | VT(512: Wv x X), fp16 out
//   QK:   320 = 32 z x 10 causal tiles: Q' x X^T, fp16 out, scale 1/32
//   PV:   256 blocks x 2 passes (tile_m pairs (3,0),(2,1)): P x VT^T, fp32 out
// ---------------------------------------------------------------------------
template <int MODE>
__global__ __launch_bounds__(512, 4) void mega(
    const u16* __restrict__ dataH, const u16* __restrict__ WvH,
    const u16* __restrict__ WqT, const u16* __restrict__ WkT,
    u16* __restrict__ MTp, u16* __restrict__ Qp, u16* __restrict__ VTa,
    u16* __restrict__ S16, const u16* __restrict__ P16,
    float* __restrict__ outF)
{
    const int C = 1024, T = 1024, HC = 8192;
    const int nb = (MODE == M_MT ? 128 : MODE == M_PROJ ? 1024 :
                    MODE == M_QK ? 320 : 256);
    const int chunk = nb >> 3;
    const int phys = blockIdx.x;
    const int o = (phys & 7) * chunk + (phys >> 3);   // XCD-chunked remap

    __shared__ u16 lds[4 * 8192];  // 64 KB: halfbase(db,mat) = ((db<<1)|mat)*16KB
    const char* ldsc = (const char*)lds;

    const int t = threadIdx.x, w = t >> 6, l = t & 63;
    const int wm = w >> 2, wn = w & 3;
    const int frow = l & 15, fch = l >> 4;
    const int clin = w * 64 + l;
    const int srow = clin >> 2;
    const int sch = (clin & 3) ^ ((clin >> 3) & 3);

    const int NPASS = (MODE == M_PV) ? 2 : 1;

    for (int pass = 0; pass < NPASS; ++pass) {
        const u16 *Ab, *Bb;
        int lda, ldb, ldc, NT, tile_m, tile_n;
        float scale = 1.0f;
        u16* out16 = nullptr;
        float* out32 = nullptr;

        if (MODE == M_MT) {
            const int h = o >> 4, r = o & 15;
            tile_m = r >> 2; tile_n = r & 3;
            Ab = WkT + (size_t)h * C * C + (size_t)tile_m * 256 * C;
            Bb = WqT + (size_t)h * C * C + (size_t)tile_n * 256 * C;
            lda = C; ldb = C; ldc = C;
            out16 = MTp + (size_t)h * C * C;
            NT = 32;
        } else if (MODE == M_PROJ) {
            const int g = o >> 9, r = o & 511;
            if (g == 0) {   // Q'[t][h*C+c'] = sum_c X[t][c] MT_h[c'][c]
                const int s = r >> 6, ww = r & 63;   // 8x8 super-tiles
                tile_n = (s & 3) * 8 + (ww & 7);     // 0..31 (h = n>>2)
                tile_m = (s >> 2) * 8 + (ww >> 3);   // 0..15
                Ab = dataH + (size_t)tile_m * 256 * C;
                Bb = MTp + (size_t)(tile_n >> 2) * C * C + (size_t)(tile_n & 3) * 256 * C;
                lda = C; ldb = C; ldc = HC;
                out16 = Qp;
                NT = 32;
            } else {        // VT[z][c][t] = sum_k Wv[h][c][k] X[b][t][k]
                const int vz = r >> 4, rem = r & 15;
                tile_n = rem & 3; tile_m = rem >> 2;
                Ab = WvH + (size_t)(vz & 7) * C * C + (size_t)tile_m * 256 * C;
                Bb = dataH + (size_t)(vz >> 3) * T * C + (size_t)tile_n * 256 * C;
                lda = C; ldb = C; ldc = T;
                out16 = VTa + (size_t)vz * C * T;
                NT = 32;
            }
        } else if (MODE == M_QK) {
            const int qz = o / 10, j = o - qz * 10;
            tile_m = (j >= 1) + (j >= 3) + (j >= 6);
            tile_n = j - (tile_m == 0 ? 0 : tile_m == 1 ? 1 : tile_m == 2 ? 3 : 6);
            Ab = Qp + (size_t)(qz >> 3) * T * HC + (size_t)(qz & 7) * C
                    + (size_t)tile_m * 256 * HC;
            Bb = dataH + (size_t)(qz >> 3) * T * C + (size_t)tile_n * 256 * C;
            lda = HC; ldb = C; ldc = T;
            out16 = S16 + (size_t)qz * T * T;
            scale = 1.0f / 32.0f;
            NT = 32;
        } else {            // PV, paired: pass0 m in {3,2}, pass1 m in {0,1}
            const int pz = o >> 3, j = o & 7, x = j & 3, hi = j >> 2;
            tile_m = (pass == 0) ? (hi ? 2 : 3) : (hi ? 1 : 0);
            tile_n = x;
            Ab = P16 + (size_t)pz * T * T + (size_t)tile_m * 256 * T;
            Bb = VTa + (size_t)pz * C * T + (size_t)tile_n * 256 * T;
            lda = T; ldb = T; ldc = HC;
            out32 = outF + (size_t)(pz >> 3) * T * HC + (size_t)(pz & 7) * C;
            NT = (tile_m + 1) * 8;   // K-steps of 32: 8..32
        }

        const long eA = (long)srow * lda + sch * 8;
        const long eB = (long)srow * ldb + sch * 8;

        f32x4 acc[8][4] = {};
        f16x8 af[4], bf[4];

        // stage K-step TT (A + B tiles, 256x32 each, 4 gloads/thread total)
#define STAGE(DB, TT) do {                                                     \
        const u16* gA_ = Ab + (size_t)(TT) * 32 + eA;                          \
        const u16* hbA_ = lds + (((DB) << 1) << 13);                           \
        gload_lds16(gA_, hbA_, (unsigned)(w * 64 * 16));                       \
        gload_lds16(gA_ + (size_t)128 * lda, hbA_,                             \
                    (unsigned)((512 + w * 64) * 16));                          \
        const u16* gB_ = Bb + (size_t)(TT) * 32 + eB;                          \
        const u16* hbB_ = lds + ((((DB) << 1) | 1) << 13);                     \
        gload_lds16(gB_, hbB_, (unsigned)(w * 64 * 16));                       \
        gload_lds16(gB_ + (size_t)128 * ldb, hbB_,                             \
                    (unsigned)((512 + w * 64) * 16));                          \
    } while (0)

        // swizzled fragment read from half (DB, MAT)
#define RD(DB, MAT, ROW)                                                       \
    (*(const f16x8*)(ldsc + ((((DB) << 1) | (MAT)) << 14) +                    \
                     (((unsigned)((ROW) * 64 + fch * 16)) ^                    \
                      ((((ROW) >> 1) & 3) << 4))))

        // prologue: steps 0,1 -> dbuf 0,1; wait step0 (4 of 8 loads)
        STAGE(0, 0);
        STAGE(1, 1);
        asm volatile("s_waitcnt vmcnt(4)");
        __builtin_amdgcn_sched_barrier(0);
        __builtin_amdgcn_s_barrier();

        for (int tt = 0; tt < NT; ++tt) {
            const int cb = tt & 1;
            // ---- P0: B-frags + A-frags 0..3, MFMA mi 0..3 ----
#pragma unroll
            for (int ni = 0; ni < 4; ++ni)
                bf[ni] = RD(cb, 1, wn * 64 + ni * 16 + frow);
#pragma unroll
            for (int m4 = 0; m4 < 4; ++m4)
                af[m4] = RD(cb, 0, wm * 128 + m4 * 16 + frow);
            __builtin_amdgcn_sched_barrier(0);
            __builtin_amdgcn_s_barrier();
            asm volatile("s_waitcnt lgkmcnt(0)");
            __builtin_amdgcn_sched_barrier(0);
            __builtin_amdgcn_s_setprio(1);
#pragma unroll
            for (int m4 = 0; m4 < 4; ++m4)
#pragma unroll
                for (int ni = 0; ni < 4; ++ni)
                    acc[m4][ni] = __builtin_amdgcn_mfma_f32_16x16x32_f16(
                        af[m4], bf[ni], acc[m4][ni], 0, 0, 0);
            __builtin_amdgcn_s_setprio(0);
            __builtin_amdgcn_sched_barrier(0);
            __builtin_amdgcn_s_barrier();
            // ---- P1: A-frags 4..7, stage tt+2 (after lgkm0: WAR-safe), MFMA mi 4..7 ----
#pragma unroll
            for (int m4 = 0; m4 < 4; ++m4)
                af[m4] = RD(cb, 0, wm * 128 + (4 + m4) * 16 + frow);
            __builtin_amdgcn_sched_barrier(0);
            __builtin_amdgcn_s_barrier();
            asm volatile("s_waitcnt lgkmcnt(0)");
            __builtin_amdgcn_sched_barrier(0);
            if (tt + 2 < NT) STAGE(cb, tt + 2);
            __builtin_amdgcn_sched_barrier(0);
            __builtin_amdgcn_s_setprio(1);
#pragma unroll
            for (int m4 = 0; m4 < 4; ++m4)
#pragma unroll
                for (int ni = 0; ni < 4; ++ni)
                    acc[4 + m4][ni] = __builtin_amdgcn_mfma_f32_16x16x32_f16(
                        af[m4], bf[ni], acc[4 + m4][ni], 0, 0, 0);
            __builtin_amdgcn_s_setprio(0);
            __builtin_amdgcn_sched_barrier(0);
            if (tt + 2 < NT) {
                asm volatile("s_waitcnt vmcnt(4)");   // tt+1 landed; tt+2 in flight
                __builtin_amdgcn_sched_barrier(0);
            } else if (tt + 1 < NT) {
                asm volatile("s_waitcnt vmcnt(0)");
                __builtin_amdgcn_sched_barrier(0);
            }
            __builtin_amdgcn_s_barrier();
        }
#undef RD
#undef STAGE

        // epilogue: C/D layout col = l&15, row = (l>>4)*4 + r
        const int r0 = (l >> 4) * 4, cc = l & 15;
#pragma unroll
        for (int mi = 0; mi < 8; ++mi) {
#pragma unroll
            for (int r = 0; r < 4; ++r) {
                size_t grow = (size_t)(tile_m * 256 + wm * 128 + mi * 16 + r0 + r);
#pragma unroll
                for (int ni = 0; ni < 4; ++ni) {
                    int gcol = tile_n * 256 + wn * 64 + ni * 16 + cc;
                    float v = acc[mi][ni][r] * scale;
                    if (MODE == M_PV)
                        out32[grow * ldc + gcol] = v;
                    else
                        out16[grow * ldc + gcol] = f2h(v);
                }
            }
        }
    }
}

// ---------------------------------------------------------------------------
// single-pass causal softmax, fp16 S -> fp16 P; zero-fill to round256(t+1).
// ---------------------------------------------------------------------------
__global__ __launch_bounds__(256) void softmax16(
    const u16* __restrict__ S, u16* __restrict__ P)
{
    const int T = 1024;
    const int tq = blockIdx.x, z = blockIdx.y;
    const u16* row = S + ((size_t)z * T + tq) * T;
    u16* prow = P + ((size_t)z * T + tq) * T;
    const int n = tq + 1, tid = threadIdx.x, i0 = tid * 4;
    const int nw = ((tq >> 8) + 1) << 8;

    ushort4 v = ((const ushort4*)row)[tid];
    float e0 = (i0 + 0 < n) ? h2f(v.x) : -1e30f;
    float e1 = (i0 + 1 < n) ? h2f(v.y) : -1e30f;
    float e2 = (i0 + 2 < n) ? h2f(v.z) : -1e30f;
    float e3 = (i0 + 3 < n) ? h2f(v.w) : -1e30f;

    float m = fmaxf(fmaxf(e0, e1), fmaxf(e2, e3));
#pragma unroll
    for (int o = 1; o < 64; o <<= 1) m = fmaxf(m, __shfl_xor(m, o));
    __shared__ float red[4];
    if ((tid & 63) == 0) red[tid >> 6] = m;
    __syncthreads();
    m = fmaxf(fmaxf(red[0], red[1]), fmaxf(red[2], red[3]));

    float p0 = __expf(e0 - m), p1 = __expf(e1 - m);
    float p2 = __expf(e2 - m), p3 = __expf(e3 - m);
    float s = p0 + p1 + p2 + p3;
#pragma unroll
    for (int o = 1; o < 64; o <<= 1) s += __shfl_xor(s, o);
    __shared__ float red2[4];
    if ((tid & 63) == 0) red2[tid >> 6] = s;
    __syncthreads();
    const float inv = 1.0f / (red2[0] + red2[1] + red2[2] + red2[3]);

    if (i0 < nw) {
        ushort4 o4;
        o4.x = f2h(p0 * inv); o4.y = f2h(p1 * inv);
        o4.z = f2h(p2 * inv); o4.w = f2h(p3 * inv);
        ((ushort4*)prow)[tid] = o4;
    }
}

// ---------------------------------------------------------------------------
// setup: z<16 -> per-head transpose-cast of Wq/Wk (f32 [d][c] -> f16 [c][d]);
// z==16 -> data cast; z==17 -> Wv cast. grid (32,32,18), block (32,8).
// ---------------------------------------------------------------------------
__global__ __launch_bounds__(256) void cast_setup(
    const float* __restrict__ data, const float* __restrict__ Wq,
    const float* __restrict__ Wk, const float* __restrict__ Wv,
    u16* __restrict__ dataH, u16* __restrict__ WqT,
    u16* __restrict__ WkT, u16* __restrict__ WvH)
{
    const int z = blockIdx.z, tx = threadIdx.x, ty = threadIdx.y;
    if (z < 16) {
        const int h = z & 7;
        const float* src = ((z >> 3) ? Wk : Wq) + (size_t)h * 1048576;
        u16* dst = ((z >> 3) ? WkT : WqT) + (size_t)h * 1048576;
        const int r0 = blockIdx.y * 32, c0 = blockIdx.x * 32;
        __shared__ float tile[32][33];
        for (int i = ty; i < 32; i += 8)
            tile[i][tx] = src[(size_t)(r0 + i) * 1024 + c0 + tx];
        __syncthreads();
        for (int i = ty; i < 32; i += 8)
            dst[(size_t)(c0 + i) * 1024 + r0 + tx] = f2h(tile[tx][i]);
    } else {
        const int tid = ty * 32 + tx;
        const int bid = blockIdx.y * 32 + blockIdx.x;   // 0..1023
        const int reps = (z == 16) ? 4 : 8;             // 1M / 2M float4
        const float* src = (z == 16) ? data : Wv;
        u16* dst = (z == 16) ? dataH : WvH;
        for (int k2 = 0; k2 < reps; ++k2) {
            int i = (k2 * 1024 + bid) * 256 + tid;
            float4 v = ((const float4*)src)[i];
            ushort4 o4;
            o4.x = f2h(v.x); o4.y = f2h(v.y); o4.z = f2h(v.z); o4.w = f2h(v.w);
            ((ushort4*)dst)[i] = o4;
        }
    }
}

extern "C" void kernel_launch(void* const* d_in, const int* in_sizes, int n_in,
                              void* d_out, int out_size, void* d_ws, size_t ws_size,
                              hipStream_t stream)
{
    (void)in_sizes; (void)n_in; (void)out_size; (void)ws_size;
    const int B = 4, T = 1024, C = 1024, H = 8;
    const int BT = B * T, HC = H * C;

    const float* data = (const float*)d_in[0];
    const float* Wq = (const float*)d_in[1];
    const float* Wk = (const float*)d_in[2];
    const float* Wv = (const float*)d_in[3];
    float* out = (float*)d_out;

    // workspace (328 MiB of 512 MiB)
    char* p = (char*)d_ws;
    const size_t nData = (size_t)BT * C;      // 4M
    const size_t nW = (size_t)H * C * C;      // 8M
    const size_t nAll = (size_t)BT * HC;      // 32M
    const size_t nS = (size_t)B * H * T * T;  // 32M
    u16* dataH = (u16*)p; p += nData * 2;     //   8 MiB
    u16* WvH = (u16*)p; p += nW * 2;          //  16 MiB
    u16* WqT = (u16*)p; p += nW * 2;          //  16 MiB
    u16* WkT = (u16*)p; p += nW * 2;          //  16 MiB
    u16* MTp = (u16*)p; p += nW * 2;          //  16 MiB
    u16* Qp = (u16*)p; p += nAll * 2;         //  64 MiB
    u16* VTa = (u16*)p; p += nAll * 2;        //  64 MiB
    u16* S16 = (u16*)p; p += nS * 2;          //  64 MiB
    u16* P16 = (u16*)p; p += nS * 2;          //  64 MiB

    cast_setup<<<dim3(32, 32, 18), dim3(32, 8), 0, stream>>>(
        data, Wq, Wk, Wv, dataH, WqT, WkT, WvH);

    mega<M_MT><<<dim3(128), dim3(512), 0, stream>>>(
        dataH, WvH, WqT, WkT, MTp, Qp, VTa, S16, P16, out);

    mega<M_PROJ><<<dim3(1024), dim3(512), 0, stream>>>(
        dataH, WvH, WqT, WkT, MTp, Qp, VTa, S16, P16, out);

    mega<M_QK><<<dim3(320), dim3(512), 0, stream>>>(
        dataH, WvH, WqT, WkT, MTp, Qp, VTa, S16, P16, out);

    softmax16<<<dim3(T, B * H), dim3(256), 0, stream>>>(S16, P16);

    mega<M_PV><<<dim3(256), dim3(512), 0, stream>>>(
        dataH, WvH, WqT, WkT, MTp, Qp, VTa, S16, P16, out);
}

// Round 10
// 364.626 us; speedup vs baseline: 5.8321x; 5.8321x over previous
//
#include <hip/hip_runtime.h>
#include <hip/hip_fp16.h>

// ---------------------------------------------------------------------------
// Heads: per-head QKV projections + causal attention, B=4 T=1024 C=1024 H=8.
// Round 10: revert to round-8 GEMM core (256x256, BK=64, 8-phase counted
// vmcnt, 128 KB LDS, 1 block/CU — measured ~925 TF @K=1024, at reference
// level). Round-9's 2-block/CU BK=32 core is abandoned: half-cache-line reads
// + L2 overflow caused 20x HBM overfetch.
// New: round-exact dispatch packing using VT tiles as filler:
//   cast -> {MT 128 + VT 64}=256 (1 round) -> Q' 512 (2 rounds)
//        -> {QK 320 + VT 448}=768 (3 rounds) -> softmax -> PV 256.
// ---------------------------------------------------------------------------

typedef unsigned short u16;
typedef _Float16 f16x8 __attribute__((ext_vector_type(8)));
typedef float f32x4 __attribute__((ext_vector_type(4)));

__device__ __forceinline__ u16 f2h(float f) {
    union { __half h; u16 u; } cv;
    cv.h = __float2half(f);
    return cv.u;
}
__device__ __forceinline__ float h2f(u16 u) {
    union { __half h; u16 u; } cv;
    cv.u = u;
    return __half2float(cv.h);
}

// global -> LDS direct copy, 16B/lane (wave-uniform LDS base + lane*16).
__device__ __forceinline__ void gload_lds16(const u16* g, const u16* lds_base, unsigned off_bytes) {
    unsigned a32 = (unsigned)(uintptr_t)((const char*)lds_base + off_bytes);
    a32 = __builtin_amdgcn_readfirstlane(a32);
    __builtin_amdgcn_global_load_lds(
        (const __attribute__((address_space(1))) void*)(uintptr_t)g,
        (__attribute__((address_space(3))) void*)a32,
        16, 0, 0);
}

#define M_A 0   // MT(128) + VT(64)   = 192 blocks (1 round)
#define M_B 1   // Q'(512)            = 512 blocks (2 rounds)
#define M_C 2   // QK(320) + VT(448)  = 768 blocks (3 rounds)
#define M_PV 3  // PV(256), paired    = 256 blocks

// ---------------------------------------------------------------------------
// mega<MODE>: 256x256 tile, BK=64, 8 waves (2Mx4N), per-wave 128x64 out.
// D = scale * A x Bt^T (operands [rows][K] fp16). Round-8 8-phase inner loop.
// ---------------------------------------------------------------------------
template <int MODE>
__global__ __launch_bounds__(512, 2) void mega(
    const u16* __restrict__ dataH, const u16* __restrict__ WvH,
    const u16* __restrict__ WqT, const u16* __restrict__ WkT,
    u16* __restrict__ MTp, u16* __restrict__ Qp, u16* __restrict__ VTa,
    u16* __restrict__ S16, const u16* __restrict__ P16,
    float* __restrict__ outF)
{
    const int C = 1024, T = 1024, HC = 8192;
    const int nb = (MODE == M_A ? 192 : MODE == M_B ? 512 :
                    MODE == M_C ? 768 : 256);
    const int chunk = nb >> 3;
    const int phys = blockIdx.x;
    const int o = (phys & 7) * chunk + (phys >> 3);   // XCD-chunked remap

    __shared__ u16 lds[8 * 8192];  // halfbase(db,mat,ks) = ((db<<2)|(mat<<1)|ks)*8192

    const int t = threadIdx.x, w = t >> 6, l = t & 63;
    const int wm = w >> 2, wn = w & 3;
    const int frow = l & 15, fch = l >> 4;
    const int clin = w * 64 + l;
    const int srow = clin >> 2;
    const int sch = (clin & 3) ^ ((clin >> 3) & 3);

    const int NPASS = (MODE == M_PV) ? 2 : 1;

    for (int pass = 0; pass < NPASS; ++pass) {
        const u16 *Ab, *Bb;
        int lda, ldb, ldc, NT, tile_m, tile_n;
        float scale = 1.0f;
        u16* out16 = nullptr;
        float* out32 = nullptr;

        // VT filler decode (v in [0,512)): VT[z][c][t] = sum_k Wv[h][c][k] X[b][t][k]
        int vfill = -1;
        if (MODE == M_A && o >= 128) vfill = o - 128;          // v in [0,64)
        if (MODE == M_C && o >= 320) vfill = o - 320 + 64;     // v in [64,512)

        if (vfill >= 0) {
            const int vz = vfill >> 4, rem = vfill & 15;
            tile_n = rem & 3; tile_m = rem >> 2;
            Ab = WvH + (size_t)(vz & 7) * C * C + (size_t)tile_m * 256 * C;
            Bb = dataH + (size_t)(vz >> 3) * T * C + (size_t)tile_n * 256 * C;
            lda = C; ldb = C; ldc = T;
            out16 = VTa + (size_t)vz * C * T;
            NT = 16;
        } else if (MODE == M_A) {
            // MT_h[c'][c] = sum_d WkT[c'][d] WqT[c][d]
            const int h = o >> 4, r = o & 15;
            tile_m = r >> 2; tile_n = r & 3;
            Ab = WkT + (size_t)h * C * C + (size_t)tile_m * 256 * C;
            Bb = WqT + (size_t)h * C * C + (size_t)tile_n * 256 * C;
            lda = C; ldb = C; ldc = C;
            out16 = MTp + (size_t)h * C * C;
            NT = 16;
        } else if (MODE == M_B) {
            // Q'[t][h*C+c'] = sum_c X[t][c] MT_h[c'][c], 8x8 super-tiles
            const int s = o >> 6, ww = o & 63;
            tile_n = (s & 3) * 8 + (ww & 7);     // 0..31 (h = n>>2)
            tile_m = (s >> 2) * 8 + (ww >> 3);   // 0..15
            Ab = dataH + (size_t)tile_m * 256 * C;
            Bb = MTp + (size_t)(tile_n >> 2) * C * C + (size_t)(tile_n & 3) * 256 * C;
            lda = C; ldb = C; ldc = HC;
            out16 = Qp;
            NT = 16;
        } else if (MODE == M_C) {
            // QK: S = Q' x X^T / 32, causal lower-triangle tiles
            const int qz = o / 10, j = o - qz * 10;
            tile_m = (j >= 1) + (j >= 3) + (j >= 6);
            tile_n = j - (tile_m == 0 ? 0 : tile_m == 1 ? 1 : tile_m == 2 ? 3 : 6);
            Ab = Qp + (size_t)(qz >> 3) * T * HC + (size_t)(qz & 7) * C
                    + (size_t)tile_m * 256 * HC;
            Bb = dataH + (size_t)(qz >> 3) * T * C + (size_t)tile_n * 256 * C;
            lda = HC; ldb = C; ldc = T;
            out16 = S16 + (size_t)qz * T * T;
            scale = 1.0f / 32.0f;
            NT = 16;
        } else {
            // PV, paired: pass0 m in {3,2}, pass1 m in {0,1} -> uniform 20 units
            const int pz = o >> 3, j = o & 7, x = j & 3, hi = j >> 2;
            tile_m = (pass == 0) ? (hi ? 2 : 3) : (hi ? 1 : 0);
            tile_n = x;
            Ab = P16 + (size_t)pz * T * T + (size_t)tile_m * 256 * T;
            Bb = VTa + (size_t)pz * C * T + (size_t)tile_n * 256 * T;
            lda = T; ldb = T; ldc = HC;
            out32 = outF + (size_t)(pz >> 3) * T * HC + (size_t)(pz & 7) * C;
            NT = (tile_m + 1) * 4;   // 4..16
        }

        const long eA = (long)srow * lda + sch * 8;
        const long eB = (long)srow * ldb + sch * 8;

        f32x4 acc[8][4] = {};
        f16x8 af[4], bf[4];

#define STAGE(DB, MAT, KS, TT) do {                                            \
        const u16* g_ = (MAT == 0 ? Ab + (size_t)(TT) * 64 + (KS) * 32 + eA    \
                                  : Bb + (size_t)(TT) * 64 + (KS) * 32 + eB);  \
        const u16* hb_ = lds + ((((DB) << 2) | ((MAT) << 1) | (KS)) << 13);    \
        gload_lds16(g_, hb_, (unsigned)(w * 64 * 16));                         \
        gload_lds16(g_ + (size_t)128 * (MAT == 0 ? lda : ldb), hb_,            \
                    (unsigned)((512 + w * 64) * 16));                          \
    } while (0)

#define RD(DB, MAT, KS, ROW)                                                   \
    (*(const f16x8*)((const char*)(lds + ((((DB) << 2) | ((MAT) << 1) | (KS)) << 13)) + \
                     ((unsigned)((ROW) * 64 + fch * 16) ^ ((((ROW) >> 1) & 3) << 4))))

#define VM6 do { asm volatile("s_waitcnt vmcnt(6)"); \
                 __builtin_amdgcn_sched_barrier(0); } while (0)
#define VM0 do { asm volatile("s_waitcnt vmcnt(0)"); \
                 __builtin_amdgcn_sched_barrier(0); } while (0)
#define NOPW ((void)0)

#define PH(DB, KS, MH, WAITC, ...) do {                                        \
        if ((MH) == 0) {                                                       \
            _Pragma("unroll") for (int ni = 0; ni < 4; ++ni)                   \
                bf[ni] = RD(DB, 1, KS, wn * 64 + ni * 16 + frow);              \
        }                                                                      \
        _Pragma("unroll") for (int m4 = 0; m4 < 4; ++m4)                       \
            af[m4] = RD(DB, 0, KS, wm * 128 + ((MH) * 4 + m4) * 16 + frow);    \
        __VA_ARGS__;                                                           \
        __builtin_amdgcn_sched_barrier(0);                                     \
        __builtin_amdgcn_s_barrier();                                          \
        asm volatile("s_waitcnt lgkmcnt(0)");                                  \
        __builtin_amdgcn_sched_barrier(0);                                     \
        __builtin_amdgcn_s_setprio(1);                                         \
        _Pragma("unroll") for (int m4 = 0; m4 < 4; ++m4)                       \
            _Pragma("unroll") for (int ni = 0; ni < 4; ++ni)                   \
                acc[(MH) * 4 + m4][ni] = __builtin_amdgcn_mfma_f32_16x16x32_f16( \
                    af[m4], bf[ni], acc[(MH) * 4 + m4][ni], 0, 0, 0);          \
        __builtin_amdgcn_s_setprio(0);                                         \
        __builtin_amdgcn_sched_barrier(0);                                     \
        WAITC;                                                                 \
        __builtin_amdgcn_s_barrier();                                          \
    } while (0)

        // prologue: tile0 (4 halves) + tile1 (3 halves; A-ks1 issued at p0)
        STAGE(0, 1, 0, 0); STAGE(0, 0, 0, 0); STAGE(0, 1, 1, 0); STAGE(0, 0, 1, 0);
        STAGE(1, 1, 0, 1); STAGE(1, 0, 0, 1); STAGE(1, 1, 1, 1);
        VM6;
        __builtin_amdgcn_s_barrier();

        for (int tt = 0; tt < NT; tt += 2) {
            const bool more = (tt + 2) < NT;
            PH(0, 0, 0, NOPW, STAGE(1, 0, 1, tt + 1));              // p0
            PH(0, 0, 1, NOPW, if (more) STAGE(0, 1, 0, tt + 2));    // p1
            PH(0, 1, 0, NOPW, if (more) STAGE(0, 0, 0, tt + 2));    // p2
            PH(0, 1, 1, if (more) VM6; else VM0,
                        if (more) STAGE(0, 1, 1, tt + 2));          // p3
            PH(1, 0, 0, NOPW, if (more) STAGE(0, 0, 1, tt + 2));    // p4
            PH(1, 0, 1, NOPW, if (more) STAGE(1, 1, 0, tt + 3));    // p5
            PH(1, 1, 0, NOPW, if (more) STAGE(1, 0, 0, tt + 3));    // p6
            PH(1, 1, 1, if (more) VM6; else VM0,
                        if (more) STAGE(1, 1, 1, tt + 3));          // p7
        }
#undef PH
#undef RD
#undef STAGE
#undef VM6
#undef VM0
#undef NOPW

        // epilogue: C/D layout col = l&15, row = (l>>4)*4 + r
        const int r0 = (l >> 4) * 4, cc = l & 15;
#pragma unroll
        for (int mi = 0; mi < 8; ++mi) {
#pragma unroll
            for (int r = 0; r < 4; ++r) {
                size_t grow = (size_t)(tile_m * 256 + wm * 128 + mi * 16 + r0 + r);
#pragma unroll
                for (int ni = 0; ni < 4; ++ni) {
                    int gcol = tile_n * 256 + wn * 64 + ni * 16 + cc;
                    float v = acc[mi][ni][r] * scale;
                    if (MODE == M_PV)
                        out32[grow * ldc + gcol] = v;
                    else
                        out16[grow * ldc + gcol] = f2h(v);
                }
            }
        }
    }
}

// ---------------------------------------------------------------------------
// single-pass causal softmax, fp16 S -> fp16 P; zero-fill to round256(t+1).
// ---------------------------------------------------------------------------
__global__ __launch_bounds__(256) void softmax16(
    const u16* __restrict__ S, u16* __restrict__ P)
{
    const int T = 1024;
    const int tq = blockIdx.x, z = blockIdx.y;
    const u16* row = S + ((size_t)z * T + tq) * T;
    u16* prow = P + ((size_t)z * T + tq) * T;
    const int n = tq + 1, tid = threadIdx.x, i0 = tid * 4;
    const int nw = ((tq >> 8) + 1) << 8;

    ushort4 v = ((const ushort4*)row)[tid];
    float e0 = (i0 + 0 < n) ? h2f(v.x) : -1e30f;
    float e1 = (i0 + 1 < n) ? h2f(v.y) : -1e30f;
    float e2 = (i0 + 2 < n) ? h2f(v.z) : -1e30f;
    float e3 = (i0 + 3 < n) ? h2f(v.w) : -1e30f;

    float m = fmaxf(fmaxf(e0, e1), fmaxf(e2, e3));
#pragma unroll
    for (int o = 1; o < 64; o <<= 1) m = fmaxf(m, __shfl_xor(m, o));
    __shared__ float red[4];
    if ((tid & 63) == 0) red[tid >> 6] = m;
    __syncthreads();
    m = fmaxf(fmaxf(red[0], red[1]), fmaxf(red[2], red[3]));

    float p0 = __expf(e0 - m), p1 = __expf(e1 - m);
    float p2 = __expf(e2 - m), p3 = __expf(e3 - m);
    float s = p0 + p1 + p2 + p3;
#pragma unroll
    for (int o = 1; o < 64; o <<= 1) s += __shfl_xor(s, o);
    __shared__ float red2[4];
    if ((tid & 63) == 0) red2[tid >> 6] = s;
    __syncthreads();
    const float inv = 1.0f / (red2[0] + red2[1] + red2[2] + red2[3]);

    if (i0 < nw) {
        ushort4 o4;
        o4.x = f2h(p0 * inv); o4.y = f2h(p1 * inv);
        o4.z = f2h(p2 * inv); o4.w = f2h(p3 * inv);
        ((ushort4*)prow)[tid] = o4;
    }
}

// ---------------------------------------------------------------------------
// setup: z<16 -> per-head transpose-cast of Wq/Wk (f32 [d][c] -> f16 [c][d]);
// z==16 -> data cast; z==17 -> Wv cast. grid (32,32,18), block (32,8).
// ---------------------------------------------------------------------------
__global__ __launch_bounds__(256) void cast_setup(
    const float* __restrict__ data, const float* __restrict__ Wq,
    const float* __restrict__ Wk, const float* __restrict__ Wv,
    u16* __restrict__ dataH, u16* __restrict__ WqT,
    u16* __restrict__ WkT, u16* __restrict__ WvH)
{
    const int z = blockIdx.z, tx = threadIdx.x, ty = threadIdx.y;
    if (z < 16) {
        const int h = z & 7;
        const float* src = ((z >> 3) ? Wk : Wq) + (size_t)h * 1048576;
        u16* dst = ((z >> 3) ? WkT : WqT) + (size_t)h * 1048576;
        const int r0 = blockIdx.y * 32, c0 = blockIdx.x * 32;
        __shared__ float tile[32][33];
        for (int i = ty; i < 32; i += 8)
            tile[i][tx] = src[(size_t)(r0 + i) * 1024 + c0 + tx];
        __syncthreads();
        for (int i = ty; i < 32; i += 8)
            dst[(size_t)(c0 + i) * 1024 + r0 + tx] = f2h(tile[tx][i]);
    } else {
        const int tid = ty * 32 + tx;
        const int bid = blockIdx.y * 32 + blockIdx.x;   // 0..1023
        const int reps = (z == 16) ? 4 : 8;             // 1M / 2M float4
        const float* src = (z == 16) ? data : Wv;
        u16* dst = (z == 16) ? dataH : WvH;
        for (int k2 = 0; k2 < reps; ++k2) {
            int i = (k2 * 1024 + bid) * 256 + tid;
            float4 v = ((const float4*)src)[i];
            ushort4 o4;
            o4.x = f2h(v.x); o4.y = f2h(v.y); o4.z = f2h(v.z); o4.w = f2h(v.w);
            ((ushort4*)dst)[i] = o4;
        }
    }
}

extern "C" void kernel_launch(void* const* d_in, const int* in_sizes, int n_in,
                              void* d_out, int out_size, void* d_ws, size_t ws_size,
                              hipStream_t stream)
{
    (void)in_sizes; (void)n_in; (void)out_size; (void)ws_size;
    const int B = 4, T = 1024, C = 1024, H = 8;
    const int BT = B * T, HC = H * C;

    const float* data = (const float*)d_in[0];
    const float* Wq = (const float*)d_in[1];
    const float* Wk = (const float*)d_in[2];
    const float* Wv = (const float*)d_in[3];
    float* out = (float*)d_out;

    // workspace (328 MiB of 512 MiB)
    char* p = (char*)d_ws;
    const size_t nData = (size_t)BT * C;      // 4M
    const size_t nW = (size_t)H * C * C;      // 8M
    const size_t nAll = (size_t)BT * HC;      // 32M
    const size_t nS = (size_t)B * H * T * T;  // 32M
    u16* dataH = (u16*)p; p += nData * 2;     //   8 MiB
    u16* WvH = (u16*)p; p += nW * 2;          //  16 MiB
    u16* WqT = (u16*)p; p += nW * 2;          //  16 MiB
    u16* WkT = (u16*)p; p += nW * 2;          //  16 MiB
    u16* MTp = (u16*)p; p += nW * 2;          //  16 MiB
    u16* Qp = (u16*)p; p += nAll * 2;         //  64 MiB
    u16* VTa = (u16*)p; p += nAll * 2;        //  64 MiB
    u16* S16 = (u16*)p; p += nS * 2;          //  64 MiB
    u16* P16 = (u16*)p; p += nS * 2;          //  64 MiB

    cast_setup<<<dim3(32, 32, 18), dim3(32, 8), 0, stream>>>(
        data, Wq, Wk, Wv, dataH, WqT, WkT, WvH);

    // MT(128) + VT(64) = 192 blocks -> 1 round
    mega<M_A><<<dim3(192), dim3(512), 0, stream>>>(
        dataH, WvH, WqT, WkT, MTp, Qp, VTa, S16, P16, out);

    // Q'(512) -> 2 rounds
    mega<M_B><<<dim3(512), dim3(512), 0, stream>>>(
        dataH, WvH, WqT, WkT, MTp, Qp, VTa, S16, P16, out);

    // QK(320) + VT(448) = 768 blocks -> 3 rounds
    mega<M_C><<<dim3(768), dim3(512), 0, stream>>>(
        dataH, WvH, WqT, WkT, MTp, Qp, VTa, S16, P16, out);

    softmax16<<<dim3(T, B * H), dim3(256), 0, stream>>>(S16, P16);

    // PV(256), uniform 20 K-units per block
    mega<M_PV><<<dim3(256), dim3(512), 0, stream>>>(
        dataH, WvH, WqT, WkT, MTp, Qp, VTa, S16, P16, out);
}